// Round 12
// baseline (195.752 us; speedup 1.0000x reference)
//
#include <hip/hip_runtime.h>
#include <hip/hip_bf16.h>

// Problem constants
constexpr int BB = 2;
constexpr int SS = 2048;
constexpr int EE = 1024;
constexpr int HH = 16;
constexpr int DD = 64;
constexpr int MM = BB * SS;              // 4096 rows in the projection GEMMs
constexpr int CX = MM * EE;              // 4194304 elems per X slice (2^22)
constexpr int CW = EE * EE;              // 1048576 elems per W slice (2^20)
// Q pre-scale: 1/sqrt(EMBED_DIM) * log2(e) so attention scores are base-2 logits
#define QSCALE 0.045084220027780106f

typedef __attribute__((ext_vector_type(8))) short short8;    // 8 bf16 = 4 VGPRs (MFMA A/B frag)
typedef __attribute__((ext_vector_type(4))) float floatx4;   // MFMA C/D frag
typedef __attribute__((ext_vector_type(4))) unsigned uintx4; // 4 packed bf16 pairs

union fragu { uintx4 u; short8 s; };

__device__ inline short bf16bits(float x) {
    __hip_bfloat16 h = __float2bfloat16(x);
    return *reinterpret_cast<short*>(&h);
}

__device__ inline unsigned pkbf(float a, float b) {
    return (unsigned)(unsigned short)bf16bits(a) |
           ((unsigned)(unsigned short)bf16bits(b) << 16);
}

__device__ inline float fast_exp2(float x) {
#if __has_builtin(__builtin_amdgcn_exp2f)
    return __builtin_amdgcn_exp2f(x);
#else
    return exp2f(x);
#endif
}

// Async global->LDS, 16 B per lane. LDS dest = wave-uniform base + lane*16.
__device__ inline void gl_lds16(const __hip_bfloat16* g, const short* l) {
    __builtin_amdgcn_global_load_lds(
        (const __attribute__((address_space(1))) void*)g,
        (__attribute__((address_space(3))) void*)l, 16, 0, 0);
}

// Key relabeling so the post-exp QK score fragment IS the PV A-fragment:
// LDS K row p holds global key sigma(p).
// p = [f1 f0 q1 q0 r1 r0]  ->  sigma = [f1 q1 q0 f0 r1 r0]
__device__ inline int sigma_row(int p) {
    return (p & 0x23) | ((p & 0x0C) << 1) | ((p & 0x10) >> 2);
}

#define TURN0 { __asm__ volatile("s_waitcnt vmcnt(0)" ::: "memory"); __builtin_amdgcn_s_barrier(); }

// ---------------------------------------------------------------------------
// Convert pass: f32 -> bf16, flat over 3 X slices then 3 W slices. (unchanged)
// ---------------------------------------------------------------------------
__global__ __launch_bounds__(256) void convert_kernel(
    const float* __restrict__ x0, const float* __restrict__ x1, const float* __restrict__ x2,
    const float* __restrict__ w0, const float* __restrict__ w1, const float* __restrict__ w2,
    __hip_bfloat16* __restrict__ xb, __hip_bfloat16* __restrict__ wb)
{
    const long long e = (long long)(blockIdx.x * 256 + threadIdx.x) * 8;
    const float* src;
    __hip_bfloat16* dst;
    if (e < 3LL * CX) {
        const int z = (int)(e >> 22);
        const int off = (int)(e & (CX - 1));
        src = ((z == 0) ? x0 : (z == 1) ? x1 : x2) + off;
        dst = xb + e;
    } else {
        const long long e2 = e - 3LL * CX;
        const int z = (int)(e2 >> 20);
        const int off = (int)(e2 & (CW - 1));
        src = ((z == 0) ? w0 : (z == 1) ? w1 : w2) + off;
        dst = wb + e2;
    }
    const float4 a = reinterpret_cast<const float4*>(src)[0];
    const float4 b = reinterpret_cast<const float4*>(src)[1];
    short8 r;
    r[0] = bf16bits(a.x); r[1] = bf16bits(a.y); r[2] = bf16bits(a.z); r[3] = bf16bits(a.w);
    r[4] = bf16bits(b.x); r[5] = bf16bits(b.y); r[6] = bf16bits(b.z); r[7] = bf16bits(b.w);
    *reinterpret_cast<short8*>(dst) = r;
}

// ---------------------------------------------------------------------------
// Projection GEMM — EXACT R0/R6 best-measured version (unchanged from R11).
// ---------------------------------------------------------------------------
__global__ __launch_bounds__(256) void proj_gemm(
    const __hip_bfloat16* __restrict__ xb,
    const __hip_bfloat16* __restrict__ wb,
    const float* __restrict__ bq, const float* __restrict__ bk, const float* __restrict__ bv,
    __hip_bfloat16* __restrict__ qws,
    __hip_bfloat16* __restrict__ kws,
    __hip_bfloat16* __restrict__ vtws)
{
    const int which = blockIdx.z;
    const __hip_bfloat16* A = xb + (size_t)which * CX;
    const __hip_bfloat16* W = wb + (size_t)which * CW;
    const float* bias = (which == 0) ? bq : (which == 1) ? bk : bv;

    const int m0   = blockIdx.x * 128;
    const int n0   = blockIdx.y * 128;
    const int tid  = threadIdx.x;
    const int wave = tid >> 6;
    const int lane = tid & 63;
    const int l15  = lane & 15;
    const int quad = lane >> 4;
    const int wr   = wave >> 1;
    const int wc   = wave & 1;

    __shared__ __align__(16) short As[128 * 32];   // 8 KiB, superrow-swizzled
    __shared__ __align__(16) short Bs[128 * 32];   // 8 KiB

    const int dpos  = (lane & 7) ^ (lane >> 3);
    const int drloc = 2 * (lane >> 3) + (dpos >> 2);
    const int dgran = (dpos & 3) * 8;              // k-offset in shorts

    const int rbase = (l15 >> 1) * 64;             // superrow offset within tile
    const int rslot = (((l15 & 1) * 4 + quad) ^ (l15 >> 1)) * 8;

    floatx4 acc[4][4] = {};

    for (int k0 = 0; k0 < EE; k0 += 32) {
        __syncthreads();  // WAR: previous iteration's frag reads complete
        #pragma unroll
        for (int p = 0; p < 2; ++p) {
            const int rb16 = wave * 32 + p * 16;   // 16-row issue base
            gl_lds16(A + (size_t)(m0 + rb16 + drloc) * EE + k0 + dgran, &As[rb16 * 32]);
            gl_lds16(W + (size_t)(n0 + rb16 + drloc) * EE + k0 + dgran, &Bs[rb16 * 32]);
        }
        __syncthreads();  // staging visible (drains vmcnt)

        short8 af[4], bf[4];
        #pragma unroll
        for (int mt = 0; mt < 4; ++mt)
            af[mt] = *reinterpret_cast<const short8*>(
                &As[(wr * 32 + mt * 8) * 64 + rbase + rslot]);
        #pragma unroll
        for (int nt = 0; nt < 4; ++nt)
            bf[nt] = *reinterpret_cast<const short8*>(
                &Bs[(wc * 32 + nt * 8) * 64 + rbase + rslot]);

        #pragma unroll
        for (int mt = 0; mt < 4; ++mt)
            #pragma unroll
            for (int nt = 0; nt < 4; ++nt)
                acc[mt][nt] = __builtin_amdgcn_mfma_f32_16x16x32_bf16(af[mt], bf[nt], acc[mt][nt], 0, 0, 0);
    }

    // Epilogue: C/D layout col = lane&15, row = quad*4 + r
    #pragma unroll
    for (int nt = 0; nt < 4; ++nt) {
        const int n = n0 + wc * 64 + nt * 16 + l15;
        const float bval = bias[n];
        const int h = n >> 6, d = n & 63;
        #pragma unroll
        for (int mt = 0; mt < 4; ++mt) {
            #pragma unroll
            for (int r = 0; r < 4; ++r) {
                const int m = m0 + wr * 64 + mt * 16 + quad * 4 + r;
                const int b = m >> 11;
                const int s = m & (SS - 1);
                float val = acc[mt][nt][r] + bval;
                if (which == 0) val *= QSCALE;   // fold softmax scale+log2e into Q
                const __hip_bfloat16 hv = __float2bfloat16(val);
                if (which == 0)
                    qws[(((size_t)b * HH + h) * SS + s) * DD + d] = hv;
                else if (which == 1)
                    kws[(((size_t)b * HH + h) * SS + s) * DD + d] = hv;
                else
                    vtws[(((size_t)b * HH + h) * DD + d) * SS + s] = hv;
            }
        }
    }
}

// ---------------------------------------------------------------------------
// Flash attention v10 = v6 re-decomposed into TWO INDEPENDENT 4-wave blocks
// per CU: 256 threads (2 q-groups x 2 key-halves), 128 q/block, grid 512,
// LDS 72 KB -> 2 blocks/CU. Same 8 waves/CU and same per-wave work
// (64 q x 1024 keys) as v6, but the barrier domain halves (4 waves) and the
// two resident blocks run anti-phase: one block's vmcnt(0) drain overlaps
// the other's compute (the m114 mechanism that makes proj's full-drain loop
// fast). K/V double-buffered depth-1 (LDS-forced), static period-2 unroll.
// Math/tile assignment identical to v6: sigma-permuted K, mask as additive
// MFMA C-bias, ones-MFMA denominator, no-max exp2 softmax with exact
// cross-half combine. Each wave stages 32 rows of K and V per tile
// (8 gl_lds16 issues).
// ---------------------------------------------------------------------------
#define ATTN_PF(B, T) { \
    const int kn = (T) * 64; \
    gl_lds16(Kg + (size_t)(kn + sk0) * DD + sg, Ksg + (B) * 4096 + rbA * 64); \
    gl_lds16(VTg + (size_t)(rbA + srow) * SS + kn + sg, Vsg + (B) * 4096 + rbA * 64); \
    gl_lds16(Kg + (size_t)(kn + sk1) * DD + sg, Ksg + (B) * 4096 + rbB * 64); \
    gl_lds16(VTg + (size_t)(rbB + srow) * SS + kn + sg, Vsg + (B) * 4096 + rbB * 64); \
    gl_lds16(Kg + (size_t)(kn + sk2) * DD + sg, Ksg + (B) * 4096 + rbC * 64); \
    gl_lds16(VTg + (size_t)(rbC + srow) * SS + kn + sg, Vsg + (B) * 4096 + rbC * 64); \
    gl_lds16(Kg + (size_t)(kn + sk3) * DD + sg, Ksg + (B) * 4096 + rbD * 64); \
    gl_lds16(VTg + (size_t)(rbD + srow) * SS + kn + sg, Vsg + (B) * 4096 + rbD * 64); }

#define ATTN_BODY(B, T) { \
    const int kt = (T) * 64; \
    floatx4 s[4][4]; \
    __builtin_amdgcn_s_setprio(1); \
    _Pragma("unroll") \
    for (int f = 0; f < 4; ++f) { \
        const int krow = (f * 16 + l15) * 64; \
        const short8 ka = *reinterpret_cast<const short8*>(Ksg + (B) * 4096 + krow + (quad ^ swz) * 8); \
        const short8 kb = *reinterpret_cast<const short8*>(Ksg + (B) * 4096 + krow + ((quad + 4) ^ swz) * 8); \
        const float4 mf = *reinterpret_cast<const float4*>( \
            Msb + kt + 32 * (f >> 1) + 8 * quad + 4 * (f & 1)); \
        floatx4 mb; mb[0] = mf.x; mb[1] = mf.y; mb[2] = mf.z; mb[3] = mf.w; \
        _Pragma("unroll") \
        for (int qb = 0; qb < 4; ++qb) { \
            floatx4 z = __builtin_amdgcn_mfma_f32_16x16x32_bf16(ka, qa[qb][0], mb, 0, 0, 0); \
            s[qb][f]  = __builtin_amdgcn_mfma_f32_16x16x32_bf16(kb, qa[qb][1], z, 0, 0, 0); \
        } \
    } \
    __builtin_amdgcn_s_setprio(0); \
    fragu pk[4][2]; \
    _Pragma("unroll") \
    for (int qb = 0; qb < 4; ++qb) \
        _Pragma("unroll") \
        for (int f = 0; f < 4; ++f) { \
            const float e0 = fast_exp2(s[qb][f][0]); \
            const float e1 = fast_exp2(s[qb][f][1]); \
            const float e2 = fast_exp2(s[qb][f][2]); \
            const float e3 = fast_exp2(s[qb][f][3]); \
            const int i0 = (f & 1) * 2; \
            pk[qb][f >> 1].u[i0]     = pkbf(e0, e1); \
            pk[qb][f >> 1].u[i0 + 1] = pkbf(e2, e3); \
        } \
    __builtin_amdgcn_s_setprio(1); \
    _Pragma("unroll") \
    for (int qb = 0; qb < 4; ++qb) { \
        accl[qb] = __builtin_amdgcn_mfma_f32_16x16x32_bf16(pk[qb][0].s, ones, accl[qb], 0, 0, 0); \
        accl[qb] = __builtin_amdgcn_mfma_f32_16x16x32_bf16(pk[qb][1].s, ones, accl[qb], 0, 0, 0); \
    } \
    _Pragma("unroll") \
    for (int nt = 0; nt < 4; ++nt) { \
        const int vrow = (nt * 16 + l15) * 64; \
        const short8 vb0 = *reinterpret_cast<const short8*>(Vsg + (B) * 4096 + vrow + (quad ^ swz) * 8); \
        const short8 vb1 = *reinterpret_cast<const short8*>(Vsg + (B) * 4096 + vrow + ((quad + 4) ^ swz) * 8); \
        _Pragma("unroll") \
        for (int qb = 0; qb < 4; ++qb) { \
            acc[qb][nt] = __builtin_amdgcn_mfma_f32_16x16x32_bf16(pk[qb][0].s, vb0, acc[qb][nt], 0, 0, 0); \
            acc[qb][nt] = __builtin_amdgcn_mfma_f32_16x16x32_bf16(pk[qb][1].s, vb1, acc[qb][nt], 0, 0, 0); \
        } \
    } \
    __builtin_amdgcn_s_setprio(0); }

__global__ __launch_bounds__(256, 2) void attn_kernel(
    const __hip_bfloat16* __restrict__ qws,
    const __hip_bfloat16* __restrict__ kws,
    const __hip_bfloat16* __restrict__ vtws,
    const int* __restrict__ amask,
    float* __restrict__ out)
{
    const int flatb = blockIdx.y * gridDim.x + blockIdx.x;     // 0..511
    const int bh    = 4 * (flatb & 7) + ((flatb >> 3) & 3);    // XCD-partitioned head
    const int b     = bh >> 4;
    const int q0    = (flatb >> 5) * 128;                      // 16 q-tiles of 128
    const int tid  = threadIdx.x;
    const int wave = tid >> 6;
    const int lane = tid & 63;
    const int l15  = lane & 15;
    const int quad = lane >> 4;
    const int qg   = wave & 1;        // q-group: 64 q rows
    const int kh   = wave >> 1;       // key-half: tiles kh*16 .. kh*16+15

    const __hip_bfloat16* Q   = qws  + (size_t)bh * SS * DD;
    const __hip_bfloat16* Kg  = kws  + (size_t)bh * SS * DD + (size_t)kh * 1024 * DD;
    const __hip_bfloat16* VTg = vtws + (size_t)bh * DD * SS + (size_t)kh * 1024;
    const int* msk = amask + b * SS;

    // LDS pool: Ks 4 bufs (2/kh-group) | Vs 4 bufs | Ms bias. 72 KB total.
    __shared__ __align__(16) short SM[8 * 4096 + 4096];
    short* Ksg = &SM[kh * 2 * 4096];
    short* Vsg = &SM[(4 + kh * 2) * 4096];
    float* Msf = reinterpret_cast<float*>(&SM[8 * 4096]);
    const float* Msb = Msf + kh * 1024;

    // Stage mask once as ADDITIVE bias: valid -> 0, masked -> -1e30
    #pragma unroll
    for (int i = 0; i < 2; ++i) {
        const int j = tid + i * 256;
        const int4 m4 = reinterpret_cast<const int4*>(msk)[j];
        float4 f4;
        f4.x = m4.x ? 0.f : -1e30f;
        f4.y = m4.y ? 0.f : -1e30f;
        f4.z = m4.z ? 0.f : -1e30f;
        f4.w = m4.w ? 0.f : -1e30f;
        reinterpret_cast<float4*>(Msf)[j] = f4;
    }

    // Q fragments: 4 column blocks of 16 q (64 q per wave), in regs
    const int qrow = q0 + qg * 64 + l15;
    short8 qa[4][2];
    #pragma unroll
    for (int qb = 0; qb < 4; ++qb) {
        qa[qb][0] = *reinterpret_cast<const short8*>(Q + (size_t)(qrow + qb * 16) * DD + quad * 8);
        qa[qb][1] = *reinterpret_cast<const short8*>(Q + (size_t)(qrow + qb * 16) * DD + 32 + quad * 8);
    }

    const int swz = l15 & 7;

    // ones fragment (bf16 1.0) for the l = P*ones denominator MFMA
    short8 ones;
    #pragma unroll
    for (int i = 0; i < 8; ++i) ones[i] = (short)0x3F80;

    // DMA source map (8-row issues): lane covers LDS row rb+(lane>>3),
    // source granule (lane&7)^(lane>>3); linear dest realizes slot=g^(row&7).
    // K additionally applies the sigma key relabeling to the source ROW only.
    // Wave qg stages rows qg*32 .. qg*32+31 of its kh-group's tile (4 issues
    // of 8 rows each for K and for V).
    const int srow = lane >> 3;
    const int sg   = ((lane & 7) ^ srow) * 8;
    const int rbA  = qg * 32, rbB = rbA + 8, rbC = rbA + 16, rbD = rbA + 24;
    const int sk0  = sigma_row(rbA + srow);
    const int sk1  = sigma_row(rbB + srow);
    const int sk2  = sigma_row(rbC + srow);
    const int sk3  = sigma_row(rbD + srow);

    floatx4 acc[4][4] = {};
    floatx4 accl[4] = {};

    // Prologue: stage tile 0 into buffer 0 (8 DMA issues/wave) + mask.
    ATTN_PF(0, 0);
    __asm__ volatile("s_waitcnt vmcnt(0) lgkmcnt(0)" ::: "memory");
    __builtin_amdgcn_s_barrier();

    // Depth-1 double-buffer, static period-2 unroll: body(t) prefetches
    // tile t+1 into the other buffer, computes tile t, then drains+barriers.
    // The vmcnt(0) drain is hidden by the co-resident block's compute.
    for (int t = 0; t < 14; t += 2) {
        ATTN_PF(1, t + 1); ATTN_BODY(0, t);     TURN0;
        ATTN_PF(0, t + 2); ATTN_BODY(1, t + 1); TURN0;
    }
    ATTN_PF(1, 15); ATTN_BODY(0, 14); TURN0;
    ATTN_BODY(1, 15);

    // ---- Cross-half combine: O = (O0 + O1) / (l0 + l1) ----
    __syncthreads();             // all compute done; LDS reusable
    float* CB = reinterpret_cast<float*>(&SM[0]);   // 2 regions x 20 KB
    float* R  = CB + qg * 5120;
    if (kh == 1) {
        // interleaved layout (idx*64 + lane): conflict-free b128 rows
        #pragma unroll
        for (int qb = 0; qb < 4; ++qb)
            #pragma unroll
            for (int nt = 0; nt < 4; ++nt)
                *reinterpret_cast<floatx4*>(R + ((qb * 4 + nt) * 64 + lane) * 4) = acc[qb][nt];
        #pragma unroll
        for (int qb = 0; qb < 4; ++qb)
            *reinterpret_cast<floatx4*>(R + ((16 + qb) * 64 + lane) * 4) = accl[qb];
    }
    __syncthreads();
    if (kh == 0) {
        #pragma unroll
        for (int qb = 0; qb < 4; ++qb)
            #pragma unroll
            for (int nt = 0; nt < 4; ++nt) {
                const floatx4 p = *reinterpret_cast<const floatx4*>(R + ((qb * 4 + nt) * 64 + lane) * 4);
                acc[qb][nt][0] += p[0]; acc[qb][nt][1] += p[1];
                acc[qb][nt][2] += p[2]; acc[qb][nt][3] += p[3];
            }
        const size_t obase = (size_t)bh * SS * DD;
        #pragma unroll
        for (int qb = 0; qb < 4; ++qb) {
            const floatx4 pl = *reinterpret_cast<const floatx4*>(R + ((16 + qb) * 64 + lane) * 4);
            float inv[4];
            #pragma unroll
            for (int r = 0; r < 4; ++r)
                inv[r] = 1.f / (accl[qb][r] + pl[r]);
            #pragma unroll
            for (int nt = 0; nt < 4; ++nt)
                #pragma unroll
                for (int r = 0; r < 4; ++r) {
                    const int qq = q0 + qg * 64 + qb * 16 + quad * 4 + r;
                    const int d  = nt * 16 + l15;
                    out[obase + (size_t)qq * DD + d] = acc[qb][nt][r] * inv[r];
                }
        }
    }
}

extern "C" void kernel_launch(void* const* d_in, const int* in_sizes, int n_in,
                              void* d_out, int out_size, void* d_ws, size_t ws_size,
                              hipStream_t stream) {
    const float* q    = (const float*)d_in[0];
    const float* k    = (const float*)d_in[1];
    const float* v    = (const float*)d_in[2];
    const int*   mask = (const int*)d_in[3];
    const float* Wq   = (const float*)d_in[4];
    const float* bq   = (const float*)d_in[5];
    const float* Wk   = (const float*)d_in[6];
    const float* bk   = (const float*)d_in[7];
    const float* Wv   = (const float*)d_in[8];
    const float* bv   = (const float*)d_in[9];
    float* out = (float*)d_out;

    // Workspace (shorts): qws | kws | vtws | Xbf(3) | Wbf(3)
    __hip_bfloat16* qws  = (__hip_bfloat16*)d_ws;
    __hip_bfloat16* kws  = qws + (size_t)CX;
    __hip_bfloat16* vtws = kws + (size_t)CX;
    __hip_bfloat16* xb   = vtws + (size_t)CX;
    __hip_bfloat16* wb   = xb + (size_t)3 * CX;

    const int cvt_blocks = (3 * CX + 3 * CW) / (256 * 8);
    convert_kernel<<<dim3(cvt_blocks), 256, 0, stream>>>(q, k, v, Wq, Wk, Wv, xb, wb);
    proj_gemm<<<dim3(MM / 128, EE / 128, 3), 256, 0, stream>>>(
        xb, wb, bq, bk, bv, qws, kws, vtws);
    attn_kernel<<<dim3(SS / 128, BB * HH), 256, 0, stream>>>(
        qws, kws, vtws, mask, out);
}

// Round 13
// 190.945 us; speedup vs baseline: 1.0252x; 1.0252x over previous
//
#include <hip/hip_runtime.h>
#include <hip/hip_bf16.h>

// Problem constants
constexpr int BB = 2;
constexpr int SS = 2048;
constexpr int EE = 1024;
constexpr int HH = 16;
constexpr int DD = 64;
constexpr int MM = BB * SS;              // 4096 rows in the projection GEMMs
constexpr int CX = MM * EE;              // 4194304 elems per X slice (2^22)
constexpr int CW = EE * EE;              // 1048576 elems per W slice (2^20)
// Q pre-scale: 1/sqrt(EMBED_DIM) * log2(e) so attention scores are base-2 logits
#define QSCALE 0.045084220027780106f

typedef __attribute__((ext_vector_type(8))) short short8;    // 8 bf16 = 4 VGPRs (MFMA A/B frag)
typedef __attribute__((ext_vector_type(4))) float floatx4;   // MFMA C/D frag
typedef __attribute__((ext_vector_type(4))) unsigned uintx4; // 4 packed bf16 pairs

union fragu { uintx4 u; short8 s; };

__device__ inline short bf16bits(float x) {
    __hip_bfloat16 h = __float2bfloat16(x);
    return *reinterpret_cast<short*>(&h);
}

__device__ inline unsigned pkbf(float a, float b) {
    return (unsigned)(unsigned short)bf16bits(a) |
           ((unsigned)(unsigned short)bf16bits(b) << 16);
}

// Cheap bf16 pair-pack for the attention P values: round-half-up via bit
// arithmetic (5 VALU ops vs ~12-15 for two full RNE __float2bfloat16 chains).
// Valid here because exp2 outputs are finite and non-negative (no NaN/inf
// handling needed); differs from RNE only on exact ties (<=0.5 ulp). The
// ones-MFMA denominator consumes the SAME packed values, so normalization
// is self-consistent.
__device__ inline unsigned pk_rnu(float a, float b) {
    const unsigned au = (__builtin_bit_cast(unsigned, a) + 0x8000u) >> 16;
    const unsigned bu = (__builtin_bit_cast(unsigned, b) + 0x8000u) & 0xFFFF0000u;
    return bu | au;
}

__device__ inline float fast_exp2(float x) {
#if __has_builtin(__builtin_amdgcn_exp2f)
    return __builtin_amdgcn_exp2f(x);
#else
    return exp2f(x);
#endif
}

// Async global->LDS, 16 B per lane. LDS dest = wave-uniform base + lane*16.
__device__ inline void gl_lds16(const __hip_bfloat16* g, const short* l) {
    __builtin_amdgcn_global_load_lds(
        (const __attribute__((address_space(1))) void*)g,
        (__attribute__((address_space(3))) void*)l, 16, 0, 0);
}

// Key relabeling so the post-exp QK score fragment IS the PV A-fragment:
// LDS K row p holds global key sigma(p).
// p = [f1 f0 q1 q0 r1 r0]  ->  sigma = [f1 q1 q0 f0 r1 r0]
__device__ inline int sigma_row(int p) {
    return (p & 0x23) | ((p & 0x0C) << 1) | ((p & 0x10) >> 2);
}

#define TURN0 { __asm__ volatile("s_waitcnt vmcnt(0)" ::: "memory"); __builtin_amdgcn_s_barrier(); }

// ---------------------------------------------------------------------------
// Convert pass: f32 -> bf16, flat over 3 X slices then 3 W slices. (unchanged;
// full RNE conversion kept — these values feed 1024-long GEMM dot products.)
// ---------------------------------------------------------------------------
__global__ __launch_bounds__(256) void convert_kernel(
    const float* __restrict__ x0, const float* __restrict__ x1, const float* __restrict__ x2,
    const float* __restrict__ w0, const float* __restrict__ w1, const float* __restrict__ w2,
    __hip_bfloat16* __restrict__ xb, __hip_bfloat16* __restrict__ wb)
{
    const long long e = (long long)(blockIdx.x * 256 + threadIdx.x) * 8;
    const float* src;
    __hip_bfloat16* dst;
    if (e < 3LL * CX) {
        const int z = (int)(e >> 22);
        const int off = (int)(e & (CX - 1));
        src = ((z == 0) ? x0 : (z == 1) ? x1 : x2) + off;
        dst = xb + e;
    } else {
        const long long e2 = e - 3LL * CX;
        const int z = (int)(e2 >> 20);
        const int off = (int)(e2 & (CW - 1));
        src = ((z == 0) ? w0 : (z == 1) ? w1 : w2) + off;
        dst = wb + e2;
    }
    const float4 a = reinterpret_cast<const float4*>(src)[0];
    const float4 b = reinterpret_cast<const float4*>(src)[1];
    short8 r;
    r[0] = bf16bits(a.x); r[1] = bf16bits(a.y); r[2] = bf16bits(a.z); r[3] = bf16bits(a.w);
    r[4] = bf16bits(b.x); r[5] = bf16bits(b.y); r[6] = bf16bits(b.z); r[7] = bf16bits(b.w);
    *reinterpret_cast<short8*>(dst) = r;
}

// ---------------------------------------------------------------------------
// Projection GEMM — EXACT R0/R6 best-measured version (unchanged).
// ---------------------------------------------------------------------------
__global__ __launch_bounds__(256) void proj_gemm(
    const __hip_bfloat16* __restrict__ xb,
    const __hip_bfloat16* __restrict__ wb,
    const float* __restrict__ bq, const float* __restrict__ bk, const float* __restrict__ bv,
    __hip_bfloat16* __restrict__ qws,
    __hip_bfloat16* __restrict__ kws,
    __hip_bfloat16* __restrict__ vtws)
{
    const int which = blockIdx.z;
    const __hip_bfloat16* A = xb + (size_t)which * CX;
    const __hip_bfloat16* W = wb + (size_t)which * CW;
    const float* bias = (which == 0) ? bq : (which == 1) ? bk : bv;

    const int m0   = blockIdx.x * 128;
    const int n0   = blockIdx.y * 128;
    const int tid  = threadIdx.x;
    const int wave = tid >> 6;
    const int lane = tid & 63;
    const int l15  = lane & 15;
    const int quad = lane >> 4;
    const int wr   = wave >> 1;
    const int wc   = wave & 1;

    __shared__ __align__(16) short As[128 * 32];   // 8 KiB, superrow-swizzled
    __shared__ __align__(16) short Bs[128 * 32];   // 8 KiB

    const int dpos  = (lane & 7) ^ (lane >> 3);
    const int drloc = 2 * (lane >> 3) + (dpos >> 2);
    const int dgran = (dpos & 3) * 8;              // k-offset in shorts

    const int rbase = (l15 >> 1) * 64;             // superrow offset within tile
    const int rslot = (((l15 & 1) * 4 + quad) ^ (l15 >> 1)) * 8;

    floatx4 acc[4][4] = {};

    for (int k0 = 0; k0 < EE; k0 += 32) {
        __syncthreads();  // WAR: previous iteration's frag reads complete
        #pragma unroll
        for (int p = 0; p < 2; ++p) {
            const int rb16 = wave * 32 + p * 16;   // 16-row issue base
            gl_lds16(A + (size_t)(m0 + rb16 + drloc) * EE + k0 + dgran, &As[rb16 * 32]);
            gl_lds16(W + (size_t)(n0 + rb16 + drloc) * EE + k0 + dgran, &Bs[rb16 * 32]);
        }
        __syncthreads();  // staging visible (drains vmcnt)

        short8 af[4], bf[4];
        #pragma unroll
        for (int mt = 0; mt < 4; ++mt)
            af[mt] = *reinterpret_cast<const short8*>(
                &As[(wr * 32 + mt * 8) * 64 + rbase + rslot]);
        #pragma unroll
        for (int nt = 0; nt < 4; ++nt)
            bf[nt] = *reinterpret_cast<const short8*>(
                &Bs[(wc * 32 + nt * 8) * 64 + rbase + rslot]);

        #pragma unroll
        for (int mt = 0; mt < 4; ++mt)
            #pragma unroll
            for (int nt = 0; nt < 4; ++nt)
                acc[mt][nt] = __builtin_amdgcn_mfma_f32_16x16x32_bf16(af[mt], bf[nt], acc[mt][nt], 0, 0, 0);
    }

    // Epilogue: C/D layout col = lane&15, row = quad*4 + r
    #pragma unroll
    for (int nt = 0; nt < 4; ++nt) {
        const int n = n0 + wc * 64 + nt * 16 + l15;
        const float bval = bias[n];
        const int h = n >> 6, d = n & 63;
        #pragma unroll
        for (int mt = 0; mt < 4; ++mt) {
            #pragma unroll
            for (int r = 0; r < 4; ++r) {
                const int m = m0 + wr * 64 + mt * 16 + quad * 4 + r;
                const int b = m >> 11;
                const int s = m & (SS - 1);
                float val = acc[mt][nt][r] + bval;
                if (which == 0) val *= QSCALE;   // fold softmax scale+log2e into Q
                const __hip_bfloat16 hv = __float2bfloat16(val);
                if (which == 0)
                    qws[(((size_t)b * HH + h) * SS + s) * DD + d] = hv;
                else if (which == 1)
                    kws[(((size_t)b * HH + h) * SS + s) * DD + d] = hv;
                else
                    vtws[(((size_t)b * HH + h) * DD + d) * SS + s] = hv;
            }
        }
    }
}

// ---------------------------------------------------------------------------
// Flash attention v11 = v10 (two independent 4-wave blocks/CU, R12) with the
// SM-phase bf16 pack switched from full RNE __float2bfloat16 chains to the
// 5-op round-half-up bit pack (pk_rnu) — exp2 outputs are finite/nonneg so
// the NaN/denorm handling in the library cvt is dead weight. ~150 fewer VALU
// insts per body. All else identical to R12: 256 threads (2 q-groups x 2
// key-halves), 128 q/block, grid 512, LDS 72 KB -> 2 blocks/CU, depth-1
// double-buffer with TURN0 (drain hidden by the co-resident block), mask as
// additive MFMA C-bias, sigma-permuted K, ones-MFMA denominator.
// ---------------------------------------------------------------------------
#define ATTN_PF(B, T) { \
    const int kn = (T) * 64; \
    gl_lds16(Kg + (size_t)(kn + sk0) * DD + sg, Ksg + (B) * 4096 + rbA * 64); \
    gl_lds16(VTg + (size_t)(rbA + srow) * SS + kn + sg, Vsg + (B) * 4096 + rbA * 64); \
    gl_lds16(Kg + (size_t)(kn + sk1) * DD + sg, Ksg + (B) * 4096 + rbB * 64); \
    gl_lds16(VTg + (size_t)(rbB + srow) * SS + kn + sg, Vsg + (B) * 4096 + rbB * 64); \
    gl_lds16(Kg + (size_t)(kn + sk2) * DD + sg, Ksg + (B) * 4096 + rbC * 64); \
    gl_lds16(VTg + (size_t)(rbC + srow) * SS + kn + sg, Vsg + (B) * 4096 + rbC * 64); \
    gl_lds16(Kg + (size_t)(kn + sk3) * DD + sg, Ksg + (B) * 4096 + rbD * 64); \
    gl_lds16(VTg + (size_t)(rbD + srow) * SS + kn + sg, Vsg + (B) * 4096 + rbD * 64); }

#define ATTN_BODY(B, T) { \
    const int kt = (T) * 64; \
    floatx4 s[4][4]; \
    __builtin_amdgcn_s_setprio(1); \
    _Pragma("unroll") \
    for (int f = 0; f < 4; ++f) { \
        const int krow = (f * 16 + l15) * 64; \
        const short8 ka = *reinterpret_cast<const short8*>(Ksg + (B) * 4096 + krow + (quad ^ swz) * 8); \
        const short8 kb = *reinterpret_cast<const short8*>(Ksg + (B) * 4096 + krow + ((quad + 4) ^ swz) * 8); \
        const float4 mf = *reinterpret_cast<const float4*>( \
            Msb + kt + 32 * (f >> 1) + 8 * quad + 4 * (f & 1)); \
        floatx4 mb; mb[0] = mf.x; mb[1] = mf.y; mb[2] = mf.z; mb[3] = mf.w; \
        _Pragma("unroll") \
        for (int qb = 0; qb < 4; ++qb) { \
            floatx4 z = __builtin_amdgcn_mfma_f32_16x16x32_bf16(ka, qa[qb][0], mb, 0, 0, 0); \
            s[qb][f]  = __builtin_amdgcn_mfma_f32_16x16x32_bf16(kb, qa[qb][1], z, 0, 0, 0); \
        } \
    } \
    __builtin_amdgcn_s_setprio(0); \
    fragu pk[4][2]; \
    _Pragma("unroll") \
    for (int qb = 0; qb < 4; ++qb) \
        _Pragma("unroll") \
        for (int f = 0; f < 4; ++f) { \
            const float e0 = fast_exp2(s[qb][f][0]); \
            const float e1 = fast_exp2(s[qb][f][1]); \
            const float e2 = fast_exp2(s[qb][f][2]); \
            const float e3 = fast_exp2(s[qb][f][3]); \
            const int i0 = (f & 1) * 2; \
            pk[qb][f >> 1].u[i0]     = pk_rnu(e0, e1); \
            pk[qb][f >> 1].u[i0 + 1] = pk_rnu(e2, e3); \
        } \
    __builtin_amdgcn_s_setprio(1); \
    _Pragma("unroll") \
    for (int qb = 0; qb < 4; ++qb) { \
        accl[qb] = __builtin_amdgcn_mfma_f32_16x16x32_bf16(pk[qb][0].s, ones, accl[qb], 0, 0, 0); \
        accl[qb] = __builtin_amdgcn_mfma_f32_16x16x32_bf16(pk[qb][1].s, ones, accl[qb], 0, 0, 0); \
    } \
    _Pragma("unroll") \
    for (int nt = 0; nt < 4; ++nt) { \
        const int vrow = (nt * 16 + l15) * 64; \
        const short8 vb0 = *reinterpret_cast<const short8*>(Vsg + (B) * 4096 + vrow + (quad ^ swz) * 8); \
        const short8 vb1 = *reinterpret_cast<const short8*>(Vsg + (B) * 4096 + vrow + ((quad + 4) ^ swz) * 8); \
        _Pragma("unroll") \
        for (int qb = 0; qb < 4; ++qb) { \
            acc[qb][nt] = __builtin_amdgcn_mfma_f32_16x16x32_bf16(pk[qb][0].s, vb0, acc[qb][nt], 0, 0, 0); \
            acc[qb][nt] = __builtin_amdgcn_mfma_f32_16x16x32_bf16(pk[qb][1].s, vb1, acc[qb][nt], 0, 0, 0); \
        } \
    } \
    __builtin_amdgcn_s_setprio(0); }

__global__ __launch_bounds__(256, 2) void attn_kernel(
    const __hip_bfloat16* __restrict__ qws,
    const __hip_bfloat16* __restrict__ kws,
    const __hip_bfloat16* __restrict__ vtws,
    const int* __restrict__ amask,
    float* __restrict__ out)
{
    const int flatb = blockIdx.y * gridDim.x + blockIdx.x;     // 0..511
    const int bh    = 4 * (flatb & 7) + ((flatb >> 3) & 3);    // XCD-partitioned head
    const int b     = bh >> 4;
    const int q0    = (flatb >> 5) * 128;                      // 16 q-tiles of 128
    const int tid  = threadIdx.x;
    const int wave = tid >> 6;
    const int lane = tid & 63;
    const int l15  = lane & 15;
    const int quad = lane >> 4;
    const int qg   = wave & 1;        // q-group: 64 q rows
    const int kh   = wave >> 1;       // key-half: tiles kh*16 .. kh*16+15

    const __hip_bfloat16* Q   = qws  + (size_t)bh * SS * DD;
    const __hip_bfloat16* Kg  = kws  + (size_t)bh * SS * DD + (size_t)kh * 1024 * DD;
    const __hip_bfloat16* VTg = vtws + (size_t)bh * DD * SS + (size_t)kh * 1024;
    const int* msk = amask + b * SS;

    // LDS pool: Ks 4 bufs (2/kh-group) | Vs 4 bufs | Ms bias. 72 KB total.
    __shared__ __align__(16) short SM[8 * 4096 + 4096];
    short* Ksg = &SM[kh * 2 * 4096];
    short* Vsg = &SM[(4 + kh * 2) * 4096];
    float* Msf = reinterpret_cast<float*>(&SM[8 * 4096]);
    const float* Msb = Msf + kh * 1024;

    // Stage mask once as ADDITIVE bias: valid -> 0, masked -> -1e30
    #pragma unroll
    for (int i = 0; i < 2; ++i) {
        const int j = tid + i * 256;
        const int4 m4 = reinterpret_cast<const int4*>(msk)[j];
        float4 f4;
        f4.x = m4.x ? 0.f : -1e30f;
        f4.y = m4.y ? 0.f : -1e30f;
        f4.z = m4.z ? 0.f : -1e30f;
        f4.w = m4.w ? 0.f : -1e30f;
        reinterpret_cast<float4*>(Msf)[j] = f4;
    }

    // Q fragments: 4 column blocks of 16 q (64 q per wave), in regs
    const int qrow = q0 + qg * 64 + l15;
    short8 qa[4][2];
    #pragma unroll
    for (int qb = 0; qb < 4; ++qb) {
        qa[qb][0] = *reinterpret_cast<const short8*>(Q + (size_t)(qrow + qb * 16) * DD + quad * 8);
        qa[qb][1] = *reinterpret_cast<const short8*>(Q + (size_t)(qrow + qb * 16) * DD + 32 + quad * 8);
    }

    const int swz = l15 & 7;

    // ones fragment (bf16 1.0) for the l = P*ones denominator MFMA
    short8 ones;
    #pragma unroll
    for (int i = 0; i < 8; ++i) ones[i] = (short)0x3F80;

    // DMA source map (8-row issues): lane covers LDS row rb+(lane>>3),
    // source granule (lane&7)^(lane>>3); linear dest realizes slot=g^(row&7).
    // K additionally applies the sigma key relabeling to the source ROW only.
    // Wave qg stages rows qg*32 .. qg*32+31 of its kh-group's tile (4 issues
    // of 8 rows each for K and for V).
    const int srow = lane >> 3;
    const int sg   = ((lane & 7) ^ srow) * 8;
    const int rbA  = qg * 32, rbB = rbA + 8, rbC = rbA + 16, rbD = rbA + 24;
    const int sk0  = sigma_row(rbA + srow);
    const int sk1  = sigma_row(rbB + srow);
    const int sk2  = sigma_row(rbC + srow);
    const int sk3  = sigma_row(rbD + srow);

    floatx4 acc[4][4] = {};
    floatx4 accl[4] = {};

    // Prologue: stage tile 0 into buffer 0 (8 DMA issues/wave) + mask.
    ATTN_PF(0, 0);
    __asm__ volatile("s_waitcnt vmcnt(0) lgkmcnt(0)" ::: "memory");
    __builtin_amdgcn_s_barrier();

    // Depth-1 double-buffer, static period-2 unroll: body(t) prefetches
    // tile t+1 into the other buffer, computes tile t, then drains+barriers.
    // The vmcnt(0) drain is hidden by the co-resident block's compute.
    for (int t = 0; t < 14; t += 2) {
        ATTN_PF(1, t + 1); ATTN_BODY(0, t);     TURN0;
        ATTN_PF(0, t + 2); ATTN_BODY(1, t + 1); TURN0;
    }
    ATTN_PF(1, 15); ATTN_BODY(0, 14); TURN0;
    ATTN_BODY(1, 15);

    // ---- Cross-half combine: O = (O0 + O1) / (l0 + l1) ----
    __syncthreads();             // all compute done; LDS reusable
    float* CB = reinterpret_cast<float*>(&SM[0]);   // 2 regions x 20 KB
    float* R  = CB + qg * 5120;
    if (kh == 1) {
        // interleaved layout (idx*64 + lane): conflict-free b128 rows
        #pragma unroll
        for (int qb = 0; qb < 4; ++qb)
            #pragma unroll
            for (int nt = 0; nt < 4; ++nt)
                *reinterpret_cast<floatx4*>(R + ((qb * 4 + nt) * 64 + lane) * 4) = acc[qb][nt];
        #pragma unroll
        for (int qb = 0; qb < 4; ++qb)
            *reinterpret_cast<floatx4*>(R + ((16 + qb) * 64 + lane) * 4) = accl[qb];
    }
    __syncthreads();
    if (kh == 0) {
        #pragma unroll
        for (int qb = 0; qb < 4; ++qb)
            #pragma unroll
            for (int nt = 0; nt < 4; ++nt) {
                const floatx4 p = *reinterpret_cast<const floatx4*>(R + ((qb * 4 + nt) * 64 + lane) * 4);
                acc[qb][nt][0] += p[0]; acc[qb][nt][1] += p[1];
                acc[qb][nt][2] += p[2]; acc[qb][nt][3] += p[3];
            }
        const size_t obase = (size_t)bh * SS * DD;
        #pragma unroll
        for (int qb = 0; qb < 4; ++qb) {
            const floatx4 pl = *reinterpret_cast<const floatx4*>(R + ((16 + qb) * 64 + lane) * 4);
            float inv[4];
            #pragma unroll
            for (int r = 0; r < 4; ++r)
                inv[r] = 1.f / (accl[qb][r] + pl[r]);
            #pragma unroll
            for (int nt = 0; nt < 4; ++nt)
                #pragma unroll
                for (int r = 0; r < 4; ++r) {
                    const int qq = q0 + qg * 64 + qb * 16 + quad * 4 + r;
                    const int d  = nt * 16 + l15;
                    out[obase + (size_t)qq * DD + d] = acc[qb][nt][r] * inv[r];
                }
        }
    }
}

extern "C" void kernel_launch(void* const* d_in, const int* in_sizes, int n_in,
                              void* d_out, int out_size, void* d_ws, size_t ws_size,
                              hipStream_t stream) {
    const float* q    = (const float*)d_in[0];
    const float* k    = (const float*)d_in[1];
    const float* v    = (const float*)d_in[2];
    const int*   mask = (const int*)d_in[3];
    const float* Wq   = (const float*)d_in[4];
    const float* bq   = (const float*)d_in[5];
    const float* Wk   = (const float*)d_in[6];
    const float* bk   = (const float*)d_in[7];
    const float* Wv   = (const float*)d_in[8];
    const float* bv   = (const float*)d_in[9];
    float* out = (float*)d_out;

    // Workspace (shorts): qws | kws | vtws | Xbf(3) | Wbf(3)
    __hip_bfloat16* qws  = (__hip_bfloat16*)d_ws;
    __hip_bfloat16* kws  = qws + (size_t)CX;
    __hip_bfloat16* vtws = kws + (size_t)CX;
    __hip_bfloat16* xb   = vtws + (size_t)CX;
    __hip_bfloat16* wb   = xb + (size_t)3 * CX;

    const int cvt_blocks = (3 * CX + 3 * CW) / (256 * 8);
    convert_kernel<<<dim3(cvt_blocks), 256, 0, stream>>>(q, k, v, Wq, Wk, Wv, xb, wb);
    proj_gemm<<<dim3(MM / 128, EE / 128, 3), 256, 0, stream>>>(
        xb, wb, bq, bk, bv, qws, kws, vtws);
    attn_kernel<<<dim3(SS / 128, BB * HH), 256, 0, stream>>>(
        qws, kws, vtws, mask, out);
}